// Round 2
// 272.559 us; speedup vs baseline: 1.0602x; 1.0602x over previous
//
#include <hip/hip_runtime.h>

#define NU 4096
#define NI 8192
#define ND 64
#define NTOT 12288
#define CT 8           // top split-K chunks  (K=NU,  ck=512)
#define CB 16          // bottom split-K chunks (K=NI, ck=512)
#define BROW 520       // u16 per staged dense row (512 + 8 pad -> even LDS spread)

// Adjacency bits become bf16 2.0 (0x4000, built by multiply-spread);
// dense operands are pre-scaled by 0.5. 2.0 * (d*0.5) == d exactly
// (power-of-2 exponent arithmetic), so accumulation is bit-identical
// to the 1.0 * d formulation.
#define DSC 0.5f

typedef unsigned short u16;
typedef unsigned int u32;
typedef unsigned long long u64;

__device__ __forceinline__ u16 f2bf(float f) {
    union { float f; u32 u; } v; v.f = f;
    u32 u = v.u;
    u += 0x7FFFu + ((u >> 16) & 1u);   // round-to-nearest-even
    return (u16)(u >> 16);
}

typedef short frag8 __attribute__((ext_vector_type(8)));
typedef float f32x4 __attribute__((ext_vector_type(4)));

// ---------------------------------------------------------------------------
// K0: edge (int32 0/1) -> bit-packed A AND AT in one pass. Block = 256 rows
// x 512 cols. int4 loads, lane-local 16-bit pack, LDS assemble, full-line
// Apk stores; in-LDS 64x64 shfl-butterfly for AT.
// ---------------------------------------------------------------------------
__global__ __launch_bounds__(256) void k_pack2(const int* __restrict__ edge,
        u64* __restrict__ Apk, u64* __restrict__ ATpk) {
    __shared__ __align__(16) u16 At[256][40];
    __shared__ __align__(16) u64 Tt[512][6];
    const int t = threadIdx.x;
    const int u0 = (blockIdx.x >> 4) * 256;
    const int i0 = (blockIdx.x & 15) * 512;
    const int cg = t & 31;
    const int rb = t >> 5;

    #pragma unroll 4
    for (int rr = 0; rr < 32; rr++) {
        const int row = rb * 32 + rr;
        const int4* p = (const int4*)(edge + (size_t)(u0 + row) * NI + i0 + cg * 16);
        u32 bits = 0;
        #pragma unroll
        for (int m = 0; m < 4; m++) {
            int4 v = p[m];
            bits |= (v.x != 0 ? 1u : 0u) << (m * 4 + 0);
            bits |= (v.y != 0 ? 1u : 0u) << (m * 4 + 1);
            bits |= (v.z != 0 ? 1u : 0u) << (m * 4 + 2);
            bits |= (v.w != 0 ? 1u : 0u) << (m * 4 + 3);
        }
        At[row][cg] = (u16)bits;
    }
    __syncthreads();

    {
        u64* dst = Apk + (size_t)(u0 + t) * 128 + (i0 >> 6);
        #pragma unroll
        for (int q = 0; q < 4; q++) {
            uint4 v = *(const uint4*)&At[t][q * 8];
            *(uint4*)(dst + q * 2) = v;
        }
    }

    {
        const int lane = t & 63, w = t >> 6;
        const u64 M[6] = {0x00000000FFFFFFFFULL, 0x0000FFFF0000FFFFULL,
                          0x00FF00FF00FF00FFULL, 0x0F0F0F0F0F0F0F0FULL,
                          0x3333333333333333ULL, 0x5555555555555555ULL};
        #pragma unroll
        for (int sc = 0; sc < 8; sc++) {
            u64 x = *(const u64*)&At[w * 64 + lane][sc * 4];
            #pragma unroll
            for (int si = 0; si < 6; si++) {
                const int s = 32 >> si;
                u64 y = __shfl_xor(x, s, 64);
                x = (lane & s) ? ((x & ~M[si]) | ((y >> s) & M[si]))
                               : ((x &  M[si]) | ((y << s) & ~M[si]));
            }
            Tt[sc * 64 + lane][w] = x;
        }
    }
    __syncthreads();
    #pragma unroll
    for (int j = 0; j < 2; j++) {
        const int item = t * 2 + j;
        ulonglong2 a = *(const ulonglong2*)&Tt[item][0];
        ulonglong2 b = *(const ulonglong2*)&Tt[item][2];
        u64* dst = ATpk + (size_t)(i0 + item) * 64 + (u0 >> 6);
        *(ulonglong2*)dst = a;
        *(ulonglong2*)(dst + 2) = b;
    }
}

// ---------------------------------------------------------------------------
// K1: degrees by popcount of packed rows + scale arrays + layer-0 B operands
// (embedding-major 64 x K, pre-scaled by 0.5). No atomics.
// ---------------------------------------------------------------------------
__global__ __launch_bounds__(256) void k_scale0(const float* __restrict__ x,
        const u64* __restrict__ Apk, const u64* __restrict__ ATpk,
        float* __restrict__ dsu, float* __restrict__ dsi,
        u16* __restrict__ BuT, u16* __restrict__ BiT) {
    __shared__ float sc[64];
    const int t = threadIdx.x;
    const int r0 = blockIdx.x * 64;
    {
        const int rl = t >> 2, part = t & 3;
        int cnt = 0;
        if (r0 < NU) {
            const u64* p = Apk + (size_t)(r0 + rl) * 128 + part * 32;
            #pragma unroll
            for (int i = 0; i < 32; i++) cnt += (int)__popcll(p[i]);
        } else {
            const u64* p = ATpk + (size_t)(r0 - NU + rl) * 64 + part * 16;
            #pragma unroll
            for (int i = 0; i < 16; i++) cnt += (int)__popcll(p[i]);
        }
        cnt += __shfl_xor(cnt, 1, 64);
        cnt += __shfl_xor(cnt, 2, 64);
        if (part == 0) {
            float s = cnt > 0 ? rsqrtf((float)cnt) : 0.f;
            sc[rl] = s;
            if (r0 < NU) dsu[r0 + rl] = s; else dsi[r0 - NU + rl] = s;
        }
    }
    __syncthreads();
    const int r4 = t >> 4, c4 = t & 15;
    float y[4][4];
    #pragma unroll
    for (int j = 0; j < 4; j++) {
        const int rl = r4 * 4 + j;
        const float s = sc[rl] * DSC;
        float4 xv = *(const float4*)(x + (size_t)(r0 + rl) * ND + c4 * 4);
        y[j][0] = xv.x * s; y[j][1] = xv.y * s;
        y[j][2] = xv.z * s; y[j][3] = xv.w * s;
    }
    u16* dst; size_t stride; int col0;
    if (r0 < NU) { dst = BuT; stride = NU; col0 = r0; }
    else         { dst = BiT; stride = NI; col0 = r0 - NU; }
    #pragma unroll
    for (int k = 0; k < 4; k++) {
        ushort4 w;
        w.x = f2bf(y[0][k]); w.y = f2bf(y[1][k]);
        w.z = f2bf(y[2][k]); w.w = f2bf(y[3][k]);
        *(ushort4*)(dst + (size_t)(c4 * 4 + k) * stride + col0 + r4 * 4) = w;
    }
}

// ---------------------------------------------------------------------------
// K2: split-K GEMM, restructured for A-fragment reuse. Block = 256 adjacency
// rows x 64 emb, 4 waves, each wave owns 64 rows (4 groups of 16, bits in
// VGPRs). Every ds_read_b128 A-fragment feeds 4 MFMAs -> LDS traffic 4x
// lower; kernel ~MFMA-bound. Bit->bf16 2.0 expansion via carry-free
// multiply-spread (p = b*(2^14+2^29); (p>>2j) & 0x40004000) -- pure C,
// no intrinsic-semantics risk. Same P layout as round 0.
// ---------------------------------------------------------------------------
__global__ __launch_bounds__(256, 2) void k_gemm(
        const u64* __restrict__ Apk, const u64* __restrict__ ATpk,
        const u16* __restrict__ BuT, const u16* __restrict__ BiT,
        float* __restrict__ Ptop, float* __restrict__ Pbot) {
    __shared__ __align__(16) u16 Bs[64 * BROW];   // 66.6 KB (reused as 64KB f32)
    const int t = threadIdx.x, bx = blockIdx.x;
    const int lane = t & 63, w = t >> 6, lr = lane & 15, lg = lane >> 4;
    const u64* abase; const u16* dense; int Kstr, wpr, kbase, pstr; float* Pout;
    if (bx < 256) {                          // top: items, K = NU
        const int tile = bx >> 3, chunk = bx & 7;
        abase = ATpk + (size_t)(tile * 256) * 64 + chunk * 8; wpr = 64;
        dense = BuT; Kstr = NU; kbase = chunk * 512; pstr = CT * 64;
        Pout = Ptop + (size_t)(tile * 256) * pstr + chunk * 64;
    } else {                                 // bottom: users, K = NI
        const int b2 = bx - 256, tile = b2 >> 4, chunk = b2 & 15;
        abase = Apk + (size_t)(tile * 256) * 128 + chunk * 8; wpr = 128;
        dense = BiT; Kstr = NI; kbase = chunk * 512; pstr = CB * 64;
        Pout = Pbot + (size_t)(tile * 256) * pstr + chunk * 64;
    }
    // stage the full 64x512 dense chunk: wave-level DMA, 1 KB per inst
    const u16* gsrc = dense + kbase;
    #pragma unroll
    for (int it = 0; it < 16; it++) {
        const int e = it * 4 + w;   // wave-uniform row
        __builtin_amdgcn_global_load_lds(
            (const __attribute__((address_space(1))) void*)
                (gsrc + (size_t)e * Kstr + lane * 8),
            (__attribute__((address_space(3))) void*)(&Bs[e * BROW]),
            16, 0, 0);
    }
    // bits for this wave's 64 adjacency rows: 4 groups x 8 u64 (64 VGPR)
    u64 aw[4][8];
    #pragma unroll
    for (int g = 0; g < 4; g++) {
        const u64* myrow = abase + (size_t)(w * 64 + g * 16 + lr) * wpr;
        #pragma unroll
        for (int q = 0; q < 4; q++) {
            ulonglong2 v = *(const ulonglong2*)(myrow + q * 2);
            aw[g][q * 2] = v.x; aw[g][q * 2 + 1] = v.y;
        }
    }
    f32x4 acc[4][4];
    #pragma unroll
    for (int g = 0; g < 4; g++)
        #pragma unroll
        for (int nt = 0; nt < 4; nt++) acc[g][nt] = f32x4{0.f, 0.f, 0.f, 0.f};
    __syncthreads();

    const int sh = lg * 8;
    #pragma unroll
    for (int kk = 0; kk < 8; kk++) {
        #pragma unroll
        for (int half = 0; half < 2; half++) {
            // expand 4 B-fragments (one per row group):
            // p = byte * (2^14 + 2^29): bit i -> positions 14+i and 29+i
            // (disjoint, carry-free, p < 2^38). (p >> 2j) & 0x40004000
            // gives u32 j with bf16 lanes {bit 2j, bit 2j+1} as 2.0/0.0.
            frag8 bf[4];
            #pragma unroll
            for (int g = 0; g < 4; g++) {
                const u32 b = (u32)(aw[g][kk] >> (sh + half * 32)) & 0xFFu;
                const u64 p = (u64)b * 0x20004000ULL;
                union { frag8 f; u32 u[4]; } bb;
                bb.u[0] = ((u32)(p     )) & 0x40004000u;
                bb.u[1] = ((u32)(p >> 2)) & 0x40004000u;
                bb.u[2] = ((u32)(p >> 4)) & 0x40004000u;
                bb.u[3] = ((u32)(p >> 6)) & 0x40004000u;
                bf[g] = bb.f;
            }
            #pragma unroll
            for (int nt = 0; nt < 4; nt++) {
                frag8 a = *(const frag8*)
                    &Bs[(nt * 16 + lr) * BROW + kk * 64 + half * 32 + sh];
                #pragma unroll
                for (int g = 0; g < 4; g++)
                    acc[g][nt] = __builtin_amdgcn_mfma_f32_16x16x32_bf16(
                        a, bf[g], acc[g][nt], 0, 0, 0);
            }
        }
    }
    // stash 256x64 f32 tile in LDS (rotation-staggered), coalesced stores
    __syncthreads();                      // all Bs reads done
    float* Fs = (float*)Bs;               // 256 rows x 16 granules x 4 f32
    #pragma unroll
    for (int g = 0; g < 4; g++) {
        const int il = w * 64 + g * 16 + lr;
        #pragma unroll
        for (int nt = 0; nt < 4; nt++) {
            const int gr = nt * 4 + lg;
            *(f32x4*)&Fs[il * 64 + (((gr + il) & 15) * 4)] = acc[g][nt];
        }
    }
    __syncthreads();
    #pragma unroll
    for (int ii = 0; ii < 16; ii++) {
        const int slot = t + ii * 256;
        const int row = slot >> 4, g = slot & 15;
        f32x4 v = *(const f32x4*)&Fs[row * 64 + (((g + row) & 15) * 4)];
        *(f32x4*)&Pout[(size_t)row * pstr + g * 4] = v;
    }
}

// ---------------------------------------------------------------------------
// K3: reduce partials (chunk-minor layout: per-row data fully contiguous),
// apply output scale, acc/out logic, emit next-layer B operands (x 0.5).
// ---------------------------------------------------------------------------
__global__ __launch_bounds__(256) void k_reduce(
        const float* __restrict__ Ptop, const float* __restrict__ Pbot,
        const float* __restrict__ dsu, const float* __restrict__ dsi,
        float* __restrict__ accbuf, u16* __restrict__ BuTn,
        u16* __restrict__ BiTn, float* __restrict__ out, int layer) {
    __shared__ u16 TB[64][24];
    const int t = threadIdx.x, bx = blockIdx.x;
    const int rl = t >> 4, e4 = t & 15;
    int grow; float so;
    float sx = 0.f, sy = 0.f, sz = 0.f, sw = 0.f;
    if (bx < 512) {
        grow = bx * 16 + rl;
        const float* p = Ptop + (size_t)grow * (CT * 64) + e4 * 4;
        #pragma unroll
        for (int c = 0; c < CT; c++) {
            float4 v = *(const float4*)(p + c * 64);
            sx += v.x; sy += v.y; sz += v.z; sw += v.w;
        }
        so = dsi[grow];
    } else {
        const int u = (bx - 512) * 16 + rl;
        grow = NI + u;
        const float* p = Pbot + (size_t)u * (CB * 64) + e4 * 4;
        #pragma unroll
        for (int c = 0; c < CB; c++) {
            float4 v = *(const float4*)(p + c * 64);
            sx += v.x; sy += v.y; sz += v.z; sw += v.w;
        }
        so = dsu[grow - NI];
    }
    float4 y;
    y.x = sx * so; y.y = sy * so; y.z = sz * so; y.w = sw * so;
    const size_t o = (size_t)grow * ND + e4 * 4;
    if (layer == 0) {
        *(float4*)(accbuf + o) = y;
    } else if (layer == 1) {
        float4 a = *(const float4*)(accbuf + o);
        a.x += y.x; a.y += y.y; a.z += y.z; a.w += y.w;
        *(float4*)(accbuf + o) = a;
    } else {
        float4 a = *(const float4*)(accbuf + o);
        a.x = (a.x + y.x) * 0.25f; a.y = (a.y + y.y) * 0.25f;
        a.z = (a.z + y.z) * 0.25f; a.w = (a.w + y.w) * 0.25f;
        *(float4*)(out + o) = a;
    }
    if (layer != 2) {
        const float fn = ((grow < NU) ? dsu[grow] : dsi[grow - NU]) * DSC;
        TB[e4 * 4 + 0][rl] = f2bf(y.x * fn);
        TB[e4 * 4 + 1][rl] = f2bf(y.y * fn);
        TB[e4 * 4 + 2][rl] = f2bf(y.z * fn);
        TB[e4 * 4 + 3][rl] = f2bf(y.w * fn);
        __syncthreads();
        if (t < 128) {
            const int e = t >> 1, h = t & 1;
            u16* dst; size_t stride; int col0;
            if (bx < 256)      { dst = BuTn; stride = NU; col0 = bx * 16; }
            else if (bx < 512) { dst = BiTn; stride = NI; col0 = bx * 16 - NU; }
            else               { dst = BiTn; stride = NI; col0 = (bx - 512) * 16 + NI - NU; }
            uint4 v = *(const uint4*)&TB[e][h * 8];
            *(uint4*)(dst + (size_t)e * stride + col0 + h * 8) = v;
        }
    }
}

extern "C" void kernel_launch(void* const* d_in, const int* in_sizes, int n_in,
                              void* d_out, int out_size, void* d_ws, size_t ws_size,
                              hipStream_t stream) {
    (void)in_sizes; (void)n_in; (void)out_size; (void)ws_size;
    const float* x    = (const float*)d_in[0];
    const int*   edge = (const int*)d_in[1];
    float* out = (float*)d_out;

    char* ws = (char*)d_ws;
    size_t off = 0;
    u64* Apk  = (u64*)(ws + off); off += (size_t)NU * (NI / 64) * 8;   // 4 MiB
    u64* ATpk = (u64*)(ws + off); off += (size_t)NI * (NU / 64) * 8;   // 4 MiB
    float* dsu = (float*)(ws + off); off += (size_t)NU * 4;
    float* dsi = (float*)(ws + off); off += (size_t)NI * 4;
    u16* BuT0 = (u16*)(ws + off); off += (size_t)ND * NU * 2;
    u16* BuT1 = (u16*)(ws + off); off += (size_t)ND * NU * 2;
    u16* BiT0 = (u16*)(ws + off); off += (size_t)ND * NI * 2;
    u16* BiT1 = (u16*)(ws + off); off += (size_t)ND * NI * 2;
    float* acc  = (float*)(ws + off); off += (size_t)NTOT * ND * 4;
    float* Ptop = (float*)(ws + off); off += (size_t)NI * CT * 64 * 4; // 16 MiB
    float* Pbot = (float*)(ws + off); off += (size_t)NU * CB * 64 * 4; // 16 MiB

    k_pack2<<<256, 256, 0, stream>>>(edge, Apk, ATpk);
    k_scale0<<<NTOT / 64, 256, 0, stream>>>(x, Apk, ATpk, dsu, dsi, BuT0, BiT0);

    k_gemm<<<512, 256, 0, stream>>>(Apk, ATpk, BuT0, BiT0, Ptop, Pbot);
    k_reduce<<<768, 256, 0, stream>>>(Ptop, Pbot, dsu, dsi, acc, BuT1, BiT1, out, 0);
    k_gemm<<<512, 256, 0, stream>>>(Apk, ATpk, BuT1, BiT1, Ptop, Pbot);
    k_reduce<<<768, 256, 0, stream>>>(Ptop, Pbot, dsu, dsi, acc, BuT0, BiT0, out, 1);
    k_gemm<<<512, 256, 0, stream>>>(Apk, ATpk, BuT0, BiT0, Ptop, Pbot);
    k_reduce<<<768, 256, 0, stream>>>(Ptop, Pbot, dsu, dsi, acc,
                                      (u16*)nullptr, (u16*)nullptr, out, 2);
}